// Round 1
// baseline (98.294 us; speedup 1.0000x reference)
//
#include <hip/hip_runtime.h>

// Smooth_Blk_Edges: x (2,1024,1024,32) fp32, BLK=(16,16), a=1.0.
// The three reference passes collapse to a local stencil on each 2x2
// block-corner group; everything else is copy / pair-smooth.

namespace {

constexpr int Hh = 1024;
constexpr int Ww = 1024;
constexpr int Cc = 32;
constexpr int C4 = Cc / 4;          // float4 per pixel = 8

__device__ __forceinline__ float4 mix2_3(const float4 a, const float4 b,
                                         const float ca, const float cb) {
    // (ca*a + cb*b) / 3
    const float inv = 1.0f / 3.0f;
    float4 r;
    r.x = (ca * a.x + cb * b.x) * inv;
    r.y = (ca * a.y + cb * b.y) * inv;
    r.z = (ca * a.z + cb * b.z) * inv;
    r.w = (ca * a.w + cb * b.w) * inv;
    return r;
}

__device__ __forceinline__ float4 mix4_5(const float4 z1, const float4 z2,
                                         const float4 z3, const float4 z4,
                                         const float c1, const float c2,
                                         const float c3, const float c4) {
    // (c1*z1 + c2*z2 + c3*z3 + c4*z4) / 5
    const float inv = 1.0f / 5.0f;
    float4 r;
    r.x = (c1 * z1.x + c2 * z2.x + c3 * z3.x + c4 * z4.x) * inv;
    r.y = (c1 * z1.y + c2 * z2.y + c3 * z3.y + c4 * z4.y) * inv;
    r.z = (c1 * z1.z + c2 * z2.z + c3 * z3.z + c4 * z4.z) * inv;
    r.w = (c1 * z1.w + c2 * z2.w + c3 * z3.w + c4 * z4.w) * inv;
    return r;
}

__global__ __launch_bounds__(256)
void smooth_blk_edges_kernel(const float4* __restrict__ in,
                             float4* __restrict__ out, const int total4) {
    const int i = blockIdx.x * blockDim.x + threadIdx.x;
    if (i >= total4) return;

    const int pix = i / C4;               // linear pixel index (b*H*W + h*W + w)
    const int w = pix % Ww;
    const int h = (pix / Ww) % Hh;

    const int hm = h & 15;
    const int wm = w & 15;
    // +1: last row/col of a block with a partner below/right
    // -1: first row/col of a block with a partner above/left
    const int he = (hm == 15 && h != Hh - 1) ? 1 : ((hm == 0 && h != 0) ? -1 : 0);
    const int we = (wm == 15 && w != Ww - 1) ? 1 : ((wm == 0 && w != 0) ? -1 : 0);

    const int sW = C4;        // float4 stride: w+1
    const int sH = Ww * C4;   // float4 stride: h+1

    float4 r;
    if (he == 0 && we == 0) {
        r = in[i];
    } else if (we == 0) {
        // vertical pair smoothing only: z1=(2x1+x2)/3 at top, z2=(x1+2x2)/3 at bottom
        if (he == 1) {
            const float4 x1 = in[i];
            const float4 x2 = in[i + sH];
            r = mix2_3(x1, x2, 2.0f, 1.0f);
        } else {
            const float4 x1 = in[i - sH];
            const float4 x2 = in[i];
            r = mix2_3(x1, x2, 1.0f, 2.0f);
        }
    } else if (he == 0) {
        // horizontal pair smoothing only (row pass is identity on this row)
        if (we == 1) {
            const float4 x1 = in[i];
            const float4 x2 = in[i + sW];
            r = mix2_3(x1, x2, 2.0f, 1.0f);
        } else {
            const float4 x1 = in[i - sW];
            const float4 x2 = in[i];
            r = mix2_3(x1, x2, 1.0f, 2.0f);
        }
    } else {
        // corner: the 2x2 group {hA,hA+1} x {wA,wA+1}; base = (hA, wA)
        const int ia = i - (he < 0 ? sH : 0) - (we < 0 ? sW : 0);
        const float4 xaa = in[ia];
        const float4 xba = in[ia + sH];
        const float4 xab = in[ia + sW];
        const float4 xbb = in[ia + sH + sW];

        // pass 1: row smoothing (vertical pairs, per column)
        const float4 vaa = mix2_3(xaa, xba, 2.0f, 1.0f);
        const float4 vba = mix2_3(xaa, xba, 1.0f, 2.0f);
        const float4 vab = mix2_3(xab, xbb, 2.0f, 1.0f);
        const float4 vbb = mix2_3(xab, xbb, 1.0f, 2.0f);

        // pass 2: column smoothing (horizontal pairs, per row)
        const float4 z1 = mix2_3(vaa, vab, 2.0f, 1.0f);  // (hA, wA)
        const float4 z2 = mix2_3(vba, vbb, 2.0f, 1.0f);  // (hB, wA)
        const float4 z3 = mix2_3(vaa, vab, 1.0f, 2.0f);  // (hA, wB)
        const float4 z4 = mix2_3(vba, vbb, 1.0f, 2.0f);  // (hB, wB)

        // pass 3: smooth_four with a=1 -> a2=1, d=5
        const int pi = (he < 0) ? 1 : 0;   // 0: hA row, 1: hB row
        const int pj = (we < 0) ? 1 : 0;   // 0: wA col, 1: wB col
        if (pi == 0 && pj == 0)      r = mix4_5(z1, z2, z3, z4,  6.0f, -1.0f, -1.0f,  1.0f);
        else if (pi == 1 && pj == 0) r = mix4_5(z1, z2, z3, z4, -1.0f,  6.0f,  1.0f, -1.0f);
        else if (pi == 0 && pj == 1) r = mix4_5(z1, z2, z3, z4, -1.0f,  1.0f,  6.0f, -1.0f);
        else                         r = mix4_5(z1, z2, z3, z4,  1.0f, -1.0f, -1.0f,  6.0f);
    }

    out[i] = r;
}

}  // namespace

extern "C" void kernel_launch(void* const* d_in, const int* in_sizes, int n_in,
                              void* d_out, int out_size, void* d_ws, size_t ws_size,
                              hipStream_t stream) {
    const float4* in = (const float4*)d_in[0];
    float4* out = (float4*)d_out;
    const int total4 = in_sizes[0] / 4;   // 16,777,216
    const int block = 256;
    const int grid = (total4 + block - 1) / block;
    smooth_blk_edges_kernel<<<grid, block, 0, stream>>>(in, out, total4);
}